// Round 7
// baseline (215.300 us; speedup 1.0000x reference)
//
#include <hip/hip_runtime.h>
#include <hip/hip_bf16.h>
#include <math.h>

typedef __attribute__((ext_vector_type(8))) short bf16x8;
typedef __attribute__((ext_vector_type(4))) float f32x4;

#define NROWS 8192
#define DIM   768
#define BM    256
#define BN    256
#define BK    64
#define NT    12   // DIM / BK

#define AS1 __attribute__((address_space(1)))
#define AS3 __attribute__((address_space(3)))

// ---- float <-> order-preserving uint key (for atomicMax on floats) ----
__device__ inline unsigned fkey(float v) {
  unsigned u = __float_as_uint(v);
  return (u & 0x80000000u) ? ~u : (u | 0x80000000u);
}
__device__ inline float funkey(unsigned k) {
  unsigned u = (k & 0x80000000u) ? (k & 0x7fffffffu) : ~k;
  return __uint_as_float(u);
}

// ---- kernel 1: row-normalize ex,ey -> bf16 matrices in workspace ----
__global__ __launch_bounds__(256) void normalize_kernel(
    const float* __restrict__ ex, const float* __restrict__ ey,
    __hip_bfloat16* __restrict__ An, __hip_bfloat16* __restrict__ Bn) {
  int row = blockIdx.x;  // 0..16383: first 8192 = ex, rest = ey
  const float* src;
  __hip_bfloat16* dst;
  if (row < NROWS) {
    src = ex + (size_t)row * DIM;
    dst = An + (size_t)row * DIM;
  } else {
    src = ey + (size_t)(row - NROWS) * DIM;
    dst = Bn + (size_t)(row - NROWS) * DIM;
  }
  int t = threadIdx.x;
  float x0 = src[t], x1 = src[t + 256], x2 = src[t + 512];
  float ss = x0 * x0 + x1 * x1 + x2 * x2;
#pragma unroll
  for (int s = 1; s < 64; s <<= 1) ss += __shfl_xor(ss, s);
  __shared__ float wsum[4];
  if ((t & 63) == 0) wsum[t >> 6] = ss;
  __syncthreads();
  float tot = wsum[0] + wsum[1] + wsum[2] + wsum[3];
  float scale = 1.0f / fmaxf(sqrtf(tot), 1e-8f);
  dst[t]       = __float2bfloat16(x0 * scale);
  dst[t + 256] = __float2bfloat16(x1 * scale);
  dst[t + 512] = __float2bfloat16(x2 * scale);
}

// ---- kernel 2: 256x256-tile 8-phase GEMM + row/col max, REGISTER-PIPELINED.
// 512 thr = 8 waves (2 row x 4 col); per-wave 128x64 output; acc[8][4] f32x4.
// LDS [2 buf][A|B][2 kh][256 rows][64 B] = 128 KB.  Phase P: {ds_read frags
// for P+1 -> stage -> sched_barrier -> MFMA on P's frags (in regs, no LDS
// wait) -> [vmcnt] -> barrier}.  LDS service of P+1 overlaps MFMA of P.
// Frag regs ping-pong: af0/af1 alternate each phase, bf0(k0)/bf1(k1) each 2.
// Stage ledger per iter (t0 even): p1:A(t0+1,1) p2:B(t0+1,1) p3:A(t0+2,0)
// p4:B(t0+2,0) p5:A(t0+2,1) p6:B(t0+2,1) p7:A(t0+3,0) p8:B(t0+3,0).
// Waits: vmcnt(2) end-p3 (drains prev-p7/8 = (t0+1,0) for p4-pref; p1/2 =
// (t0+1,1) for p6-pref), vmcnt(2) end-p7 (drains p3/4 = (t0+2,0) for p8-pref;
// p5/6 = (t0+2,1) for next-p2-pref).  Drain precedes barrier precedes the
// dependent cross-wave read.  Restage-vs-read gap >= 2 phases everywhere.
// Prologue vmcnt(4); last iter peeled with vmcnt(0) at its p3.
// Swizzle (measured 0 conflicts): 16B slot = l4 ^ ((row>>1)&3), rows 64 B.
__global__ __launch_bounds__(512, 2) void gemm_max_kernel(
    const __hip_bfloat16* __restrict__ A, const __hip_bfloat16* __restrict__ B,
    unsigned* __restrict__ rowKey, unsigned* __restrict__ colKey) {
  __shared__ __align__(16) char lds[131072];
  const int t = threadIdx.x;
  const int lane = t & 63;
  const int wid = t >> 6;       // 0..7
  const int wr = wid >> 2;      // 0..1
  const int wc = wid & 3;       // 0..3
  const int brow = blockIdx.x * BM;
  const int bcol = blockIdx.y * BN;
  const int l15 = lane & 15, l4 = lane >> 4;

  // staging source pointers (per-thread, pre-swizzled), region halves c=0/1
  const int c0L = t * 16;            // LDS byte offset within region, half 0
  const int c1L = 8192 + t * 16;     // half 1
  const int r0 = c0L >> 6, r1 = c1L >> 6;
  const int s0 = ((c0L >> 4) & 3) ^ ((r0 >> 1) & 3);
  const int s1 = ((c1L >> 4) & 3) ^ ((r1 >> 1) & 3);
  const char* gA0 = (const char*)(A + (size_t)(brow + r0) * DIM) + s0 * 16;
  const char* gA1 = (const char*)(A + (size_t)(brow + r1) * DIM) + s1 * 16;
  const char* gB0 = (const char*)(B + (size_t)(bcol + r0) * DIM) + s0 * 16;
  const char* gB1 = (const char*)(B + (size_t)(bcol + r1) * DIM) + s1 * 16;

  // fragment-read per-lane offsets; row-swizzle depends only on l15
  const int swz = ((l4 ^ ((l15 >> 1) & 3)) << 4);
  const int aoffL = (wr * 128 + l15) * 64 + swz;
  const int boffL = (wc * 64 + l15) * 64 + swz;

#define STAGE(MAT, BUF, TT, KH) do {                                      \
    const char* s0_ = ((MAT) ? gB0 : gA0) + (TT) * 128 + (KH) * 64;       \
    const char* s1_ = ((MAT) ? gB1 : gA1) + (TT) * 128 + (KH) * 64;       \
    char* d_ = lds + (BUF) * 65536 + (MAT) * 32768 + (KH) * 16384;        \
    __builtin_amdgcn_global_load_lds((const AS1 void*)s0_,                \
        (AS3 void*)(d_ + c0L), 16, 0, 0);                                 \
    __builtin_amdgcn_global_load_lds((const AS1 void*)s1_,                \
        (AS3 void*)(d_ + c1L), 16, 0, 0);                                 \
  } while (0)

#define PREF_A(DST, BUF, KK, OH)                                          \
  { _Pragma("unroll") for (int m_ = 0; m_ < 4; ++m_)                      \
      DST[m_] = *(const bf16x8*)(lds + (BUF) * 65536 + (KK) * 16384 +     \
                                 (OH) * 4096 + m_ * 1024 + aoffL); }
#define PREF_B(DST, BUF, KK)                                              \
  { _Pragma("unroll") for (int n_ = 0; n_ < 4; ++n_)                      \
      DST[n_] = *(const bf16x8*)(lds + (BUF) * 65536 + 32768 +            \
                                 (KK) * 16384 + n_ * 1024 + boffL); }

#define MFMA16(AF, BF, OH)                                                \
  { __builtin_amdgcn_s_setprio(1);                                        \
    _Pragma("unroll") for (int m_ = 0; m_ < 4; ++m_)                      \
      _Pragma("unroll") for (int n_ = 0; n_ < 4; ++n_)                    \
        acc[(OH) * 4 + m_][n_] = __builtin_amdgcn_mfma_f32_16x16x32_bf16( \
            AF[m_], BF[n_], acc[(OH) * 4 + m_][n_], 0, 0, 0);             \
    __builtin_amdgcn_s_setprio(0); }

#define SB  __builtin_amdgcn_sched_barrier(0)
#define BAR __builtin_amdgcn_s_barrier()
#define VMW(N) asm volatile("s_waitcnt vmcnt(" #N ")" ::: "memory")

  f32x4 acc[8][4];
#pragma unroll
  for (int m = 0; m < 8; ++m)
#pragma unroll
    for (int n = 0; n < 4; ++n) acc[m][n] = (f32x4)0.0f;
  bf16x8 af0[4], af1[4], bf0[4], bf1[4];

  // prologue: stage tile0 (both kh) + tile1 kh0; drain tile0; prefetch p1 frags
  STAGE(0, 0, 0, 0); STAGE(1, 0, 0, 0);
  STAGE(0, 0, 0, 1); STAGE(1, 0, 0, 1);
  STAGE(0, 1, 1, 0); STAGE(1, 1, 1, 0);
  VMW(4);
  BAR;
  PREF_A(af0, 0, 0, 0); PREF_B(bf0, 0, 0);

  for (int t0 = 0; t0 < NT - 2; t0 += 2) {
    // p1: compute (buf0,k0,OH0)
    PREF_A(af1, 0, 0, 1);                        STAGE(0, 1, t0 + 1, 1); SB;
    MFMA16(af0, bf0, 0); BAR;
    // p2: (buf0,k0,OH1)
    PREF_A(af0, 0, 1, 0); PREF_B(bf1, 0, 1);     STAGE(1, 1, t0 + 1, 1); SB;
    MFMA16(af1, bf0, 1); BAR;
    // p3: (buf0,k1,OH0)
    PREF_A(af1, 0, 1, 1);                        STAGE(0, 0, t0 + 2, 0); SB;
    MFMA16(af0, bf1, 0); VMW(2); BAR;
    // p4: (buf0,k1,OH1)
    PREF_A(af0, 1, 0, 0); PREF_B(bf0, 1, 0);     STAGE(1, 0, t0 + 2, 0); SB;
    MFMA16(af1, bf1, 1); BAR;
    // p5: (buf1,k0,OH0)
    PREF_A(af1, 1, 0, 1);                        STAGE(0, 0, t0 + 2, 1); SB;
    MFMA16(af0, bf0, 0); BAR;
    // p6: (buf1,k0,OH1)
    PREF_A(af0, 1, 1, 0); PREF_B(bf1, 1, 1);     STAGE(1, 0, t0 + 2, 1); SB;
    MFMA16(af1, bf0, 1); BAR;
    // p7: (buf1,k1,OH0)
    PREF_A(af1, 1, 1, 1);                        STAGE(0, 1, t0 + 3, 0); SB;
    MFMA16(af0, bf1, 0); VMW(2); BAR;
    // p8: (buf1,k1,OH1)
    PREF_A(af0, 0, 0, 0); PREF_B(bf0, 0, 0);     STAGE(1, 1, t0 + 3, 0); SB;
    MFMA16(af1, bf1, 1); BAR;
  }

  // peeled final iteration (t0 = NT-2): only (NT-1,kh1) still to stage
  PREF_A(af1, 0, 0, 1);                        STAGE(0, 1, NT - 1, 1); SB;
  MFMA16(af0, bf0, 0); BAR;
  PREF_A(af0, 0, 1, 0); PREF_B(bf1, 0, 1);     STAGE(1, 1, NT - 1, 1); SB;
  MFMA16(af1, bf0, 1); BAR;
  PREF_A(af1, 0, 1, 1); SB;
  MFMA16(af0, bf1, 0); VMW(0); BAR;
  PREF_A(af0, 1, 0, 0); PREF_B(bf0, 1, 0); SB;
  MFMA16(af1, bf1, 1); BAR;
  PREF_A(af1, 1, 0, 1); SB;
  MFMA16(af0, bf0, 0); BAR;
  PREF_A(af0, 1, 1, 0); PREF_B(bf1, 1, 1); SB;
  MFMA16(af1, bf0, 1); BAR;
  PREF_A(af1, 1, 1, 1); SB;
  MFMA16(af0, bf1, 0); BAR;
  SB;
  MFMA16(af1, bf1, 1);

#undef STAGE
#undef PREF_A
#undef PREF_B
#undef MFMA16
#undef SB
#undef BAR
#undef VMW

  // ---- epilogue: row/col maxes of this block's 256x256 tile ----
  // D layout (16x16x32 bf16): col = lane&15, row = (lane>>4)*4 + reg
#pragma unroll
  for (int m = 0; m < 8; ++m) {
#pragma unroll
    for (int j = 0; j < 4; ++j) {
      float v = fmaxf(fmaxf(acc[m][0][j], acc[m][1][j]),
                      fmaxf(acc[m][2][j], acc[m][3][j]));
#pragma unroll
      for (int s = 1; s < 16; s <<= 1) v = fmaxf(v, __shfl_xor(v, s));
      if (l15 == 0) {
        int grow = brow + wr * 128 + m * 16 + l4 * 4 + j;
        atomicMax(&rowKey[grow], fkey(v));
      }
    }
  }
#pragma unroll
  for (int n = 0; n < 4; ++n) {
    float v = -1e30f;
#pragma unroll
    for (int m = 0; m < 8; ++m)
#pragma unroll
      for (int j = 0; j < 4; ++j) v = fmaxf(v, acc[m][n][j]);
    v = fmaxf(v, __shfl_xor(v, 16));
    v = fmaxf(v, __shfl_xor(v, 32));
    if (l4 == 0) {
      int gcol = bcol + wc * 64 + n * 16 + l15;
      atomicMax(&colKey[gcol], fkey(v));
    }
  }
}

// ---- kernel 3: entropy terms from the max arrays ----
__global__ __launch_bounds__(256) void finalize_kernel(
    const unsigned* __restrict__ rowKey, const unsigned* __restrict__ colKey,
    float* __restrict__ out) {
  const unsigned* src = (blockIdx.x == 0) ? rowKey : colKey;
  int t = threadIdx.x;
  const float log_norm = -0.6957949819f;  // -log(0.8) - 0.5*log(2*pi)
  float s = 0.0f;
  for (int i = t; i < NROWS; i += 256) {
    float c = funkey(src[i]);
    float lp = -(c * c) * 0.78125f + log_norm;  // 1/(2*0.8^2) = 0.78125
    s += __expf(lp) * lp;
  }
#pragma unroll
  for (int sh = 1; sh < 64; sh <<= 1) s += __shfl_xor(s, sh);
  __shared__ float wsum[4];
  if ((t & 63) == 0) wsum[t >> 6] = s;
  __syncthreads();
  if (t == 0) out[blockIdx.x] = -(wsum[0] + wsum[1] + wsum[2] + wsum[3]);
}

extern "C" void kernel_launch(void* const* d_in, const int* in_sizes, int n_in,
                              void* d_out, int out_size, void* d_ws, size_t ws_size,
                              hipStream_t stream) {
  const float* ex = (const float*)d_in[0];
  const float* ey = (const float*)d_in[1];
  char* ws = (char*)d_ws;
  __hip_bfloat16* An = (__hip_bfloat16*)ws;                              // 12.6 MB
  __hip_bfloat16* Bn = (__hip_bfloat16*)(ws + (size_t)NROWS * DIM * 2);  // 12.6 MB
  unsigned* rowKey = (unsigned*)(ws + (size_t)NROWS * DIM * 4);          // 32 KB
  unsigned* colKey = rowKey + NROWS;                                     // 32 KB

  hipMemsetAsync(rowKey, 0, 2 * NROWS * sizeof(unsigned), stream);
  normalize_kernel<<<2 * NROWS, 256, 0, stream>>>(ex, ey, An, Bn);
  dim3 grid(NROWS / BM, NROWS / BN);
  gemm_max_kernel<<<grid, 512, 0, stream>>>(An, Bn, rowKey, colKey);
  finalize_kernel<<<2, 256, 0, stream>>>(rowKey, colKey, (float*)d_out);
}